// Round 1
// 764.732 us; speedup vs baseline: 2.8485x; 2.8485x over previous
//
#include <hip/hip_runtime.h>
#include <hip/hip_bf16.h>
#include <stdint.h>

// ---------------------------------------------------------------------------
// MoE top-2 with capacity, per-expert RMSNorm + SwiGLU FFN.  fp32 I/O,
// bf16 MFMA internals.  N=16384, D=768, E=8, H=2048, CAP=5120.
// Round 6: gemm1/gemm2 rebuilt on the m97 structure:
//  (1) global_load_lds width=16 staging (kills the reg-staged areg/breg live
//      range across __syncthreads that was spilling -> 3 GB of phantom
//      scratch WRITE_SIZE at VGPR_Count=64),
//  (2) linear LDS tiles + XOR swizzle done both-sides: inverse-swizzled
//      per-lane GLOBAL source offset (((l&7)^(l>>3))<<4) feeding a linear
//      LDS dest, and the matching ^((row&7)<<4) on ds_read_b128 fragments,
//  (3) bijective XCD-aware 2D chunk swizzle (gemm1: 8jn x 20rb per XCD,
//      gemm2: 12jn x 5rb per XCD) to cut cross-XCD L2 refetch,
//  (4) epilogues unchanged in spirit: LDS round-trip at padded stride 72,
//      coalesced 128B-line stores.
// ---------------------------------------------------------------------------

#define N_TOK 16384
#define D_    768
#define E_    8
#define H_    2048
#define CAP   5120
#define NK    (N_TOK * 2)
#define EPS_  1e-6f
#define LDE   72   // padded LDS row stride in u16 (epilogue staging only)

typedef unsigned short u16;
typedef __attribute__((ext_vector_type(8))) __bf16 v8bf;
typedef __attribute__((ext_vector_type(4))) float  v4f;

typedef __attribute__((address_space(3))) unsigned int lds_u32;
typedef const __attribute__((address_space(1))) unsigned int glb_u32;

__device__ __forceinline__ void gload16(const void* g, void* lds) {
    // 64 lanes x 16B -> 1KB: LDS dest = wave-uniform base + lane*16 (linear);
    // global source address is per-lane (carries the inverse swizzle).
    __builtin_amdgcn_global_load_lds((glb_u32*)g, (lds_u32*)lds, 16, 0, 0);
}

__device__ __forceinline__ float bf2f(u16 u) {
    union { uint32_t i; float f; } v; v.i = ((uint32_t)u) << 16; return v.f;
}
__device__ __forceinline__ u16 f2bf(float f) {
    union { uint32_t i; float f; } v; v.f = f;
    uint32_t r = v.i + 0x7fffu + ((v.i >> 16) & 1u);
    return (u16)(r >> 16);
}

// ---------------------------------------------------------------------------
// fp32 -> bf16 weight conversion, float4 granularity, grid-stride.
// ---------------------------------------------------------------------------
__global__ __launch_bounds__(256) void conv_bf16_kernel(
    const float* __restrict__ src, u16* __restrict__ dst, int n4)
{
    for (int i = blockIdx.x * 256 + threadIdx.x; i < n4; i += gridDim.x * 256) {
        float4 v = ((const float4*)src)[i];
        ushort4 o;
        o.x = f2bf(v.x); o.y = f2bf(v.y); o.z = f2bf(v.z); o.w = f2bf(v.w);
        ((ushort4*)dst)[i] = o;
    }
}

// ---------------------------------------------------------------------------
// Router: one wave per token; top-2; w0 = 1/(1+exp(l1-l0)).
// ---------------------------------------------------------------------------
__global__ __launch_bounds__(256) void router_kernel(
    const float* __restrict__ x, const float* __restrict__ gate_w,
    int* __restrict__ routerEx, float* __restrict__ routerW)
{
    __shared__ float gw[E_ * D_];
    int t = threadIdx.x;
    for (int i = t; i < E_ * D_; i += 256) gw[i] = gate_w[i];
    __syncthreads();
    int wv = t >> 6, l = t & 63;
    int n = blockIdx.x * 4 + wv;
    const float* xr = x + (size_t)n * D_;
    float p[E_];
#pragma unroll
    for (int e = 0; e < E_; ++e) p[e] = 0.f;
#pragma unroll
    for (int j = 0; j < 12; ++j) {
        int d = l + 64 * j;
        float xv = xr[d];
#pragma unroll
        for (int e = 0; e < E_; ++e) p[e] += xv * gw[e * D_ + d];
    }
#pragma unroll
    for (int off = 32; off > 0; off >>= 1) {
#pragma unroll
        for (int e = 0; e < E_; ++e) p[e] += __shfl_xor(p[e], off, 64);
    }
    if (l == 0) {
        int e0 = 0; float m0 = p[0];
#pragma unroll
        for (int e = 1; e < E_; ++e) if (p[e] > m0) { m0 = p[e]; e0 = e; }
        int e1 = (e0 == 0) ? 1 : 0; float m1 = p[e1];
#pragma unroll
        for (int e = 0; e < E_; ++e) if (e != e0 && p[e] > m1) { m1 = p[e]; e1 = e; }
        float w0 = 1.f / (1.f + __expf(m1 - m0));
        routerEx[2 * n] = e0; routerEx[2 * n + 1] = e1;
        routerW[2 * n] = w0; routerW[2 * n + 1] = 1.f - w0;
    }
}

// ---------------------------------------------------------------------------
// Dispatch: exact token-major (i = n*2+k) capacity ranking, single block.
// ---------------------------------------------------------------------------
__global__ __launch_bounds__(256) void dispatch_kernel(
    const int* __restrict__ routerEx, int* __restrict__ tokenSlot,
    int* __restrict__ slotToken, int* __restrict__ cnt)
{
    __shared__ int hist[256 * E_];
    int t = threadIdx.x;
    int loc[E_];
#pragma unroll
    for (int e = 0; e < E_; ++e) loc[e] = 0;
    int base = t * (NK / 256);
    for (int j = 0; j < NK / 256; ++j) {
        int ev = routerEx[base + j];
#pragma unroll
        for (int e = 0; e < E_; ++e) loc[e] += (ev == e) ? 1 : 0;
    }
#pragma unroll
    for (int e = 0; e < E_; ++e) hist[t * E_ + e] = loc[e];
    __syncthreads();
    if (t < E_) {
        int run = 0;
        for (int tt = 0; tt < 256; ++tt) { int v = hist[tt * E_ + t]; hist[tt * E_ + t] = run; run += v; }
        cnt[t] = run;
    }
    __syncthreads();
    int off[E_];
#pragma unroll
    for (int e = 0; e < E_; ++e) off[e] = hist[t * E_ + e];
    for (int j = 0; j < NK / 256; ++j) {
        int i = base + j;
        int ev = routerEx[i];
        int pos = 0;
#pragma unroll
        for (int e = 0; e < E_; ++e) { if (ev == e) { pos = off[e]; off[e] = pos + 1; } }
        if (pos < CAP) {
            int s = ev * CAP + pos;
            tokenSlot[i] = s;
            slotToken[s] = i;
        } else {
            tokenSlot[i] = -1;
        }
    }
}

// ---------------------------------------------------------------------------
// init_out: out[n] = (sum kept w) * x[n]   (per-expert path only)
// ---------------------------------------------------------------------------
__global__ __launch_bounds__(256) void init_out_kernel(
    const float* __restrict__ x, const int* __restrict__ tokenSlot,
    const float* __restrict__ routerW, float* __restrict__ out)
{
    int g = blockIdx.x * 256 + threadIdx.x;
    int n = g / 96;
    int d0 = (g - n * 96) * 8;
    float w0 = (tokenSlot[2 * n] >= 0) ? routerW[2 * n] : 0.f;
    float w1 = (tokenSlot[2 * n + 1] >= 0) ? routerW[2 * n + 1] : 0.f;
    float ws = w0 + w1;
    const float* xr = x + (size_t)n * D_ + d0;
    float* orow = out + (size_t)n * D_ + d0;
    float4 a = *(const float4*)&xr[0];
    float4 b = *(const float4*)&xr[4];
    float4 oa, ob;
    oa.x = ws * a.x; oa.y = ws * a.y; oa.z = ws * a.z; oa.w = ws * a.w;
    ob.x = ws * b.x; ob.y = ws * b.y; ob.z = ws * b.z; ob.w = ws * b.w;
    *(float4*)&orow[0] = oa;
    *(float4*)&orow[4] = ob;
}

// ---------------------------------------------------------------------------
// Gather + RMSNorm: zE[pos] = bf16(2x*rsqrt(mean((2x)^2)+eps)*nw[e]).
// e = eFixed + blockIdx.z; z rows beyond count written as zeros.
// z stays LINEAR row-major (the gemm1 stager applies the swizzle at read).
// ---------------------------------------------------------------------------
__global__ __launch_bounds__(256) void gather_norm_kernel(
    const float* __restrict__ x, const float* __restrict__ norm_w,
    const int* __restrict__ slotToken, const int* __restrict__ cnt,
    u16* __restrict__ zAll, size_t zStride, int eFixed)
{
    int e = eFixed + blockIdx.z;
    u16* zE = zAll + (size_t)blockIdx.z * zStride;
    int t = threadIdx.x, wv = t >> 6, l = t & 63;
    int pos = blockIdx.x * 4 + wv;
    int ce = min(cnt[e], CAP);
    u16* zr = zE + (size_t)pos * D_;
    if (pos >= ce) {
        ushort4 zz = { 0, 0, 0, 0 };
#pragma unroll
        for (int j = 0; j < 3; ++j) *(ushort4*)&zr[l * 4 + 256 * j] = zz;
        return;
    }
    int tok = slotToken[e * CAP + pos] >> 1;
    const float* xr = x + (size_t)tok * D_;
    float xv[12]; float ss = 0.f;
#pragma unroll
    for (int j = 0; j < 3; ++j) {
        float4 v4 = *(const float4*)&xr[l * 4 + 256 * j];
        xv[4 * j] = v4.x; xv[4 * j + 1] = v4.y; xv[4 * j + 2] = v4.z; xv[4 * j + 3] = v4.w;
        ss += v4.x * v4.x + v4.y * v4.y + v4.z * v4.z + v4.w * v4.w;
    }
#pragma unroll
    for (int off = 32; off > 0; off >>= 1) ss += __shfl_xor(ss, off, 64);
    float rs = rsqrtf(4.f * ss * (1.f / (float)D_) + EPS_);
    const float* nw = norm_w + e * D_;
#pragma unroll
    for (int j = 0; j < 3; ++j) {
        int d0 = l * 4 + 256 * j;
        float4 nv = *(const float4*)&nw[d0];
        ushort4 o;
        o.x = f2bf(2.f * xv[4 * j]     * rs * nv.x);
        o.y = f2bf(2.f * xv[4 * j + 1] * rs * nv.y);
        o.z = f2bf(2.f * xv[4 * j + 2] * rs * nv.z);
        o.w = f2bf(2.f * xv[4 * j + 3] * rs * nv.w);
        *(ushort4*)&zr[d0] = o;
    }
}

// ---------------------------------------------------------------------------
// GEMM1: gu = zE @ w13e^T, tile 128 x (64g+64u), BK=64, K=768, fused SwiGLU.
// m97 structure: global_load_lds(16B) into linear swizzled LDS, 2 barriers
// per K-step, MFMA 16x16x32.  XCD chunk swizzle 8jn x 20rb.
// ---------------------------------------------------------------------------
__global__ __launch_bounds__(256, 2) void gemm1_kernel(
    const u16* __restrict__ zAll, size_t zStride,
    const u16* __restrict__ w13All, size_t wStride,
    u16* __restrict__ actAll, size_t actStride,
    const int* __restrict__ cnt, int eFixed)
{
    // bijective XCD swizzle over the 32x40 plane: chunk = 8 jn x 20 rb
    int hw  = blockIdx.y * 32 + blockIdx.x;
    int xcd = hw & 7, cid = hw >> 3;            // cid in [0,160)
    int jn  = (xcd & 3) * 8 + (cid & 7);        // 0..31
    int rb  = (xcd >> 2) * 20 + (cid >> 3);     // 0..39
    int e   = eFixed + blockIdx.z;
    int ce  = min(cnt[e], CAP);
    if (rb * 128 >= ce) return;
    const u16* zE   = zAll   + (size_t)blockIdx.z * zStride;
    const u16* w13e = w13All + (size_t)blockIdx.z * wStride;
    u16*       actE = actAll + (size_t)blockIdx.z * actStride;

    __shared__ __align__(16) u16 smem[2 * 128 * 64];   // 32 KB, linear
    u16* As = smem;             // [128][64] u16, XOR-swizzled content
    u16* Bs = smem + 128 * 64;

    int t = threadIdx.x, w = t >> 6, l = t & 63;
    int lr  = l >> 3;                        // row within 8-row group
    int lsw = ((l & 7) ^ lr) << 4;           // inverse-swizzled src col byte

    // per-lane global sources (linear z/w13, swizzle folded into col offset)
    const char* aSrc = (const char*)zE
        + (size_t)(rb * 128 + w * 32 + lr) * (D_ * 2) + lsw;
    int rr0   = w * 32 + lr;                              // waves 0,1: g; 2,3: u
    int grow0 = (w < 2) ? (jn * 64 + rr0) : (H_ + jn * 64 + rr0 - 64);
    const char* bSrc = (const char*)w13e + (size_t)grow0 * (D_ * 2) + lsw;

    const v4f vzero = { 0.f, 0.f, 0.f, 0.f };
    v4f acc[2][8];
#pragma unroll
    for (int i = 0; i < 2; ++i)
#pragma unroll
        for (int j = 0; j < 8; ++j) acc[i][j] = vzero;

    int fr = l & 15;              // fragment row select
    int sw = (l & 7) << 4;        // read-side XOR (row&7)<<4, row&7 == l&7
    int fq = (l >> 4) << 4;       // k-quarter byte offset

    for (int kb = 0; kb < D_ / 64; ++kb) {
        __syncthreads();          // prior MFMA reads done before overwrite
#pragma unroll
        for (int i = 0; i < 4; ++i) {
            gload16(aSrc + i * (8 * D_ * 2), &As[(w * 32 + i * 8) * 64]);
            gload16(bSrc + i * (8 * D_ * 2), &Bs[(w * 32 + i * 8) * 64]);
        }
        aSrc += 128; bSrc += 128;
        __syncthreads();          // compiler drains vmcnt(0) -> LDS valid
#pragma unroll
        for (int ks = 0; ks < 2; ++ks) {
            int kby = (ks * 64 + fq) ^ sw;
            v8bf a0 = *(const v8bf*)((const char*)As + (w * 32      + fr) * 128 + kby);
            v8bf a1 = *(const v8bf*)((const char*)As + (w * 32 + 16 + fr) * 128 + kby);
            v8bf bv[8];
#pragma unroll
            for (int ct = 0; ct < 8; ++ct)
                bv[ct] = *(const v8bf*)((const char*)Bs + (ct * 16 + fr) * 128 + kby);
#pragma unroll
            for (int ct = 0; ct < 8; ++ct) {
                acc[0][ct] = __builtin_amdgcn_mfma_f32_16x16x32_bf16(a0, bv[ct], acc[0][ct], 0, 0, 0);
                acc[1][ct] = __builtin_amdgcn_mfma_f32_16x16x32_bf16(a1, bv[ct], acc[1][ct], 0, 0, 0);
            }
        }
    }
    // epilogue: act = silu(g)*u, staged in padded LDS then coalesced stores.
    __syncthreads();
    u16* ep = smem;               // [128][LDE] view, 9216 u16 <= 16384
    int colb = l & 15, rowq = (l >> 4) * 4;
#pragma unroll
    for (int rt = 0; rt < 2; ++rt) {
#pragma unroll
        for (int cg = 0; cg < 4; ++cg) {
            v4f g = acc[rt][cg], u = acc[rt][cg + 4];
#pragma unroll
            for (int r = 0; r < 4; ++r) {
                int rl = w * 32 + rt * 16 + rowq + r;
                float gv = g[r], uv = u[r];
                ep[rl * LDE + cg * 16 + colb] = f2bf(gv / (1.f + __expf(-gv)) * uv);
            }
        }
    }
    __syncthreads();
#pragma unroll
    for (int i = 0; i < 4; ++i) {
        int rl = (t >> 3) + 32 * i;
        int c0 = (t & 7) * 8;
        uint4 v = *(const uint4*)&ep[rl * LDE + c0];
        *(uint4*)&actE[(size_t)(rb * 128 + rl) * H_ + jn * 64 + c0] = v;
    }
}

// ---------------------------------------------------------------------------
// GEMM2: delta = actE @ w2e^T, tile 128 x 64, BK=64, K=2048.  Same m97
// structure.  XCD chunk swizzle 12jn x 5rb.  WRITE_DELTA ? coalesced bf16
// delta stores : coalesced fp32 RMW into out rows (serialized path).
// ---------------------------------------------------------------------------
template <bool WRITE_DELTA>
__global__ __launch_bounds__(256, 2) void gemm2_kernel(
    const u16* __restrict__ actAll, size_t actStride,
    const u16* __restrict__ w2All, size_t wStride,
    const int* __restrict__ slotToken, const float* __restrict__ routerW,
    float* __restrict__ out, u16* __restrict__ deltaAll, size_t deltaStride,
    const int* __restrict__ cnt, int eFixed)
{
    // bijective XCD swizzle over the 12x40 plane: chunk = 12 jn x 5 rb
    int hw  = blockIdx.y * 12 + blockIdx.x;
    int xcd = hw & 7, cid = hw >> 3;            // cid in [0,60)
    int jn  = cid % 12;                         // 0..11
    int rb  = xcd * 5 + cid / 12;               // 0..39
    int e   = eFixed + blockIdx.z;
    int ce  = min(cnt[e], CAP);
    if (rb * 128 >= ce) return;
    const u16* actE = actAll + (size_t)blockIdx.z * actStride;
    const u16* w2e  = w2All  + (size_t)blockIdx.z * wStride;

    __shared__ __align__(16) u16 smem[128 * 64 + 64 * 64];   // 24 KB
    u16* As = smem;             // [128][64]
    u16* Bs = smem + 128 * 64;  // [64][64]

    int t = threadIdx.x, w = t >> 6, l = t & 63;
    int lr  = l >> 3;
    int lsw = ((l & 7) ^ lr) << 4;

    const char* aSrc = (const char*)actE
        + (size_t)(rb * 128 + w * 32 + lr) * (H_ * 2) + lsw;
    const char* bSrc = (const char*)w2e
        + (size_t)(jn * 64 + w * 16 + lr) * (H_ * 2) + lsw;

    const v4f vzero = { 0.f, 0.f, 0.f, 0.f };
    v4f acc[2][4];
#pragma unroll
    for (int i = 0; i < 2; ++i)
#pragma unroll
        for (int j = 0; j < 4; ++j) acc[i][j] = vzero;

    int fr = l & 15;
    int sw = (l & 7) << 4;
    int fq = (l >> 4) << 4;

    for (int kb = 0; kb < H_ / 64; ++kb) {
        __syncthreads();
#pragma unroll
        for (int i = 0; i < 4; ++i)
            gload16(aSrc + i * (8 * H_ * 2), &As[(w * 32 + i * 8) * 64]);
#pragma unroll
        for (int i = 0; i < 2; ++i)
            gload16(bSrc + i * (8 * H_ * 2), &Bs[(w * 16 + i * 8) * 64]);
        aSrc += 128; bSrc += 128;
        __syncthreads();
#pragma unroll
        for (int ks = 0; ks < 2; ++ks) {
            int kby = (ks * 64 + fq) ^ sw;
            v8bf a0 = *(const v8bf*)((const char*)As + (w * 32      + fr) * 128 + kby);
            v8bf a1 = *(const v8bf*)((const char*)As + (w * 32 + 16 + fr) * 128 + kby);
            v8bf bv[4];
#pragma unroll
            for (int ct = 0; ct < 4; ++ct)
                bv[ct] = *(const v8bf*)((const char*)Bs + (ct * 16 + fr) * 128 + kby);
#pragma unroll
            for (int ct = 0; ct < 4; ++ct) {
                acc[0][ct] = __builtin_amdgcn_mfma_f32_16x16x32_bf16(a0, bv[ct], acc[0][ct], 0, 0, 0);
                acc[1][ct] = __builtin_amdgcn_mfma_f32_16x16x32_bf16(a1, bv[ct], acc[1][ct], 0, 0, 0);
            }
        }
    }
    // epilogue: stage bf16 delta tile in padded LDS
    __syncthreads();
    u16* ep = smem;               // [128][LDE] view, 9216 u16 <= 12288
    int colb = l & 15, rowq = (l >> 4) * 4;
#pragma unroll
    for (int rt = 0; rt < 2; ++rt) {
#pragma unroll
        for (int ct = 0; ct < 4; ++ct) {
            v4f a = acc[rt][ct];
#pragma unroll
            for (int r = 0; r < 4; ++r) {
                int rl = w * 32 + rt * 16 + rowq + r;
                ep[rl * LDE + ct * 16 + colb] = f2bf(a[r]);
            }
        }
    }
    __syncthreads();
    if (WRITE_DELTA) {
        u16* deltaE = deltaAll + (size_t)blockIdx.z * deltaStride;
#pragma unroll
        for (int i = 0; i < 4; ++i) {
            int rl = (t >> 3) + 32 * i;
            int c0 = (t & 7) * 8;
            uint4 v = *(const uint4*)&ep[rl * LDE + c0];
            *(uint4*)&deltaE[(size_t)(rb * 128 + rl) * D_ + jn * 64 + c0] = v;
        }
    } else {
        // fp32 RMW into out rows (experts serialized -> race-free)
#pragma unroll
        for (int i = 0; i < 8; ++i) {
            int rl = (t >> 4) + 16 * i;
            int grow = rb * 128 + rl;
            if (grow >= ce) continue;
            int idx = slotToken[e * CAP + grow];
            int tok = idx >> 1;
            float wg = routerW[idx];
            int c = (t & 15) * 4;
            const u16* dr = &ep[rl * LDE + c];
            float* orow = out + (size_t)tok * D_ + jn * 64 + c;
            float4 cur = *(const float4*)orow;
            cur.x += wg * bf2f(dr[0]);
            cur.y += wg * bf2f(dr[1]);
            cur.z += wg * bf2f(dr[2]);
            cur.w += wg * bf2f(dr[3]);
            *(float4*)orow = cur;
        }
    }
}

// ---------------------------------------------------------------------------
// Combine (batched path): out[n] = ws*x[n] + w0*delta[s0] + w1*delta[s1]
// ---------------------------------------------------------------------------
__global__ __launch_bounds__(256) void combine_kernel(
    const float* __restrict__ x, const u16* __restrict__ deltaBuf,
    const int* __restrict__ tokenSlot, const float* __restrict__ routerW,
    float* __restrict__ out)
{
    int g = blockIdx.x * 256 + threadIdx.x;  // one float4 per thread
    int n = g / 192;
    int d0 = (g - n * 192) * 4;
    int s0 = tokenSlot[2 * n], s1 = tokenSlot[2 * n + 1];
    float w0 = (s0 >= 0) ? routerW[2 * n] : 0.f;
    float w1 = (s1 >= 0) ? routerW[2 * n + 1] : 0.f;
    float ws = w0 + w1;
    float4 xv = *(const float4*)&x[(size_t)n * D_ + d0];
    float4 o;
    o.x = ws * xv.x; o.y = ws * xv.y; o.z = ws * xv.z; o.w = ws * xv.w;
    if (s0 >= 0) {
        ushort4 dv = *(const ushort4*)&deltaBuf[(size_t)s0 * D_ + d0];
        o.x += w0 * bf2f(dv.x); o.y += w0 * bf2f(dv.y);
        o.z += w0 * bf2f(dv.z); o.w += w0 * bf2f(dv.w);
    }
    if (s1 >= 0) {
        ushort4 dv = *(const ushort4*)&deltaBuf[(size_t)s1 * D_ + d0];
        o.x += w1 * bf2f(dv.x); o.y += w1 * bf2f(dv.y);
        o.z += w1 * bf2f(dv.z); o.w += w1 * bf2f(dv.w);
    }
    *(float4*)&out[(size_t)n * D_ + d0] = o;
}

// ---------------------------------------------------------------------------
extern "C" void kernel_launch(void* const* d_in, const int* in_sizes, int n_in,
                              void* d_out, int out_size, void* d_ws, size_t ws_size,
                              hipStream_t stream)
{
    (void)in_sizes; (void)n_in; (void)out_size;
    const float* x      = (const float*)d_in[0];
    const float* gate_w = (const float*)d_in[1];
    const float* w13    = (const float*)d_in[2];
    const float* w2     = (const float*)d_in[3];
    const float* norm_w = (const float*)d_in[4];
    float* out = (float*)d_out;

    const size_t zSlice   = (size_t)CAP * D_ * 2;       // 7.9 MB
    const size_t actSlice = (size_t)CAP * H_ * 2;       // 21 MB
    const size_t w13Slice = (size_t)2 * H_ * D_ * 2;    // 12.6 MB
    const size_t w2Slice  = (size_t)D_ * H_ * 2;        // 3.1 MB
    const size_t ctrl     = (size_t)NK * 4 * 3 + (size_t)E_ * CAP * 4 + 256;

    char* ws = (char*)d_ws;
    size_t off = 0;
    int*   routerEx  = (int*)(ws + off);   off += (size_t)NK * 4;
    float* routerW   = (float*)(ws + off); off += (size_t)NK * 4;
    int*   tokenSlot = (int*)(ws + off);   off += (size_t)NK * 4;
    int*   slotToken = (int*)(ws + off);   off += (size_t)E_ * CAP * 4;
    int*   cnt       = (int*)(ws + off);   off += 256;

    const size_t bigNeed = ctrl + E_ * (zSlice + actSlice + w13Slice + w2Slice) + E_ * zSlice /*delta*/;
    bool batched = ws_size >= bigNeed;

    router_kernel<<<N_TOK / 4, 256, 0, stream>>>(x, gate_w, routerEx, routerW);
    dispatch_kernel<<<1, 256, 0, stream>>>(routerEx, tokenSlot, slotToken, cnt);

    if (batched) {
        u16* zBuf     = (u16*)(ws + off); off += E_ * zSlice;
        u16* actBuf   = (u16*)(ws + off); off += E_ * actSlice;
        u16* deltaBuf = (u16*)(ws + off); off += E_ * zSlice;
        u16* w13bf    = (u16*)(ws + off); off += E_ * w13Slice;
        u16* w2bf     = (u16*)(ws + off); off += E_ * w2Slice;

        int n13 = E_ * 2 * H_ * D_ / 4, n2 = E_ * D_ * H_ / 4;
        conv_bf16_kernel<<<(n13 + 255) / 256, 256, 0, stream>>>(w13, w13bf, n13);
        conv_bf16_kernel<<<(n2 + 255) / 256, 256, 0, stream>>>(w2, w2bf, n2);
        gather_norm_kernel<<<dim3(CAP / 4, 1, E_), 256, 0, stream>>>(
            x, norm_w, slotToken, cnt, zBuf, zSlice / 2, 0);
        gemm1_kernel<<<dim3(H_ / 64, CAP / 128, E_), 256, 0, stream>>>(
            zBuf, zSlice / 2, w13bf, w13Slice / 2, actBuf, actSlice / 2, cnt, 0);
        gemm2_kernel<true><<<dim3(D_ / 64, CAP / 128, E_), 256, 0, stream>>>(
            actBuf, actSlice / 2, w2bf, w2Slice / 2, slotToken, routerW,
            out, deltaBuf, zSlice / 2, cnt, 0);
        combine_kernel<<<(N_TOK * (D_ / 4)) / 256, 256, 0, stream>>>(
            x, deltaBuf, tokenSlot, routerW, out);
    } else {
        u16* zE   = (u16*)(ws + off); off += zSlice;
        u16* actE = (u16*)(ws + off); off += actSlice;
        u16* w13e = (u16*)(ws + off); off += w13Slice;
        u16* w2e  = (u16*)(ws + off); off += w2Slice;

        init_out_kernel<<<(N_TOK * (D_ / 8)) / 256, 256, 0, stream>>>(x, tokenSlot, routerW, out);
        int n13 = 2 * H_ * D_ / 4, n2 = D_ * H_ / 4;
        for (int e = 0; e < E_; ++e) {
            conv_bf16_kernel<<<(n13 + 255) / 256, 256, 0, stream>>>(
                w13 + (size_t)e * 2 * H_ * D_, w13e, n13);
            conv_bf16_kernel<<<(n2 + 255) / 256, 256, 0, stream>>>(
                w2 + (size_t)e * D_ * H_, w2e, n2);
            gather_norm_kernel<<<dim3(CAP / 4, 1, 1), 256, 0, stream>>>(
                x, norm_w, slotToken, cnt, zE, 0, e);
            gemm1_kernel<<<dim3(H_ / 64, CAP / 128, 1), 256, 0, stream>>>(
                zE, 0, w13e, 0, actE, 0, cnt, e);
            gemm2_kernel<false><<<dim3(D_ / 64, CAP / 128, 1), 256, 0, stream>>>(
                actE, 0, w2e, 0, slotToken, routerW, out, (u16*)nullptr, 0, cnt, e);
        }
    }
}

// Round 2
// 708.101 us; speedup vs baseline: 3.0763x; 1.0800x over previous
//
#include <hip/hip_runtime.h>
#include <hip/hip_bf16.h>
#include <stdint.h>

// ---------------------------------------------------------------------------
// MoE top-2 with capacity, per-expert RMSNorm + SwiGLU FFN.  fp32 I/O,
// bf16 MFMA internals.  N=16384, D=768, E=8, H=2048, CAP=5120.
// Round 7:
//  (1) gemm2 widened to 128x128 output tiles (was 128x64): halves the
//      act re-stream (6 col-tiles instead of 12 over K=2048) and matches
//      gemm1's proven MFMA:ds_read shape.  Epilogue in two 64-col halves
//      through the 32KB LDS buffer.
//  (2) dispatch_kernel: routerEx staged once into LDS (u8, +1B/128 pad)
//      via coalesced global reads; both the histogram and rank passes now
//      read LDS instead of stride-128 uncoalesced HBM (single block!).
//  Carried from round 6: global_load_lds(16B) staging, both-sides XOR
//  swizzle, bijective XCD chunk swizzles, LDS round-trip epilogues.
// ---------------------------------------------------------------------------

#define N_TOK 16384
#define D_    768
#define E_    8
#define H_    2048
#define CAP   5120
#define NK    (N_TOK * 2)
#define EPS_  1e-6f
#define LDE   72   // padded LDS row stride in u16 (epilogue staging only)

typedef unsigned short u16;
typedef unsigned char  u8;
typedef __attribute__((ext_vector_type(8))) __bf16 v8bf;
typedef __attribute__((ext_vector_type(4))) float  v4f;

typedef __attribute__((address_space(3))) unsigned int lds_u32;
typedef const __attribute__((address_space(1))) unsigned int glb_u32;

__device__ __forceinline__ void gload16(const void* g, void* lds) {
    // 64 lanes x 16B -> 1KB: LDS dest = wave-uniform base + lane*16 (linear);
    // global source address is per-lane (carries the inverse swizzle).
    __builtin_amdgcn_global_load_lds((glb_u32*)g, (lds_u32*)lds, 16, 0, 0);
}

__device__ __forceinline__ float bf2f(u16 u) {
    union { uint32_t i; float f; } v; v.i = ((uint32_t)u) << 16; return v.f;
}
__device__ __forceinline__ u16 f2bf(float f) {
    union { uint32_t i; float f; } v; v.f = f;
    uint32_t r = v.i + 0x7fffu + ((v.i >> 16) & 1u);
    return (u16)(r >> 16);
}

// ---------------------------------------------------------------------------
// fp32 -> bf16 weight conversion, float4 granularity, grid-stride.
// ---------------------------------------------------------------------------
__global__ __launch_bounds__(256) void conv_bf16_kernel(
    const float* __restrict__ src, u16* __restrict__ dst, int n4)
{
    for (int i = blockIdx.x * 256 + threadIdx.x; i < n4; i += gridDim.x * 256) {
        float4 v = ((const float4*)src)[i];
        ushort4 o;
        o.x = f2bf(v.x); o.y = f2bf(v.y); o.z = f2bf(v.z); o.w = f2bf(v.w);
        ((ushort4*)dst)[i] = o;
    }
}

// ---------------------------------------------------------------------------
// Router: one wave per token; top-2; w0 = 1/(1+exp(l1-l0)).
// ---------------------------------------------------------------------------
__global__ __launch_bounds__(256) void router_kernel(
    const float* __restrict__ x, const float* __restrict__ gate_w,
    int* __restrict__ routerEx, float* __restrict__ routerW)
{
    __shared__ float gw[E_ * D_];
    int t = threadIdx.x;
    for (int i = t; i < E_ * D_; i += 256) gw[i] = gate_w[i];
    __syncthreads();
    int wv = t >> 6, l = t & 63;
    int n = blockIdx.x * 4 + wv;
    const float* xr = x + (size_t)n * D_;
    float p[E_];
#pragma unroll
    for (int e = 0; e < E_; ++e) p[e] = 0.f;
#pragma unroll
    for (int j = 0; j < 12; ++j) {
        int d = l + 64 * j;
        float xv = xr[d];
#pragma unroll
        for (int e = 0; e < E_; ++e) p[e] += xv * gw[e * D_ + d];
    }
#pragma unroll
    for (int off = 32; off > 0; off >>= 1) {
#pragma unroll
        for (int e = 0; e < E_; ++e) p[e] += __shfl_xor(p[e], off, 64);
    }
    if (l == 0) {
        int e0 = 0; float m0 = p[0];
#pragma unroll
        for (int e = 1; e < E_; ++e) if (p[e] > m0) { m0 = p[e]; e0 = e; }
        int e1 = (e0 == 0) ? 1 : 0; float m1 = p[e1];
#pragma unroll
        for (int e = 0; e < E_; ++e) if (e != e0 && p[e] > m1) { m1 = p[e]; e1 = e; }
        float w0 = 1.f / (1.f + __expf(m1 - m0));
        routerEx[2 * n] = e0; routerEx[2 * n + 1] = e1;
        routerW[2 * n] = w0; routerW[2 * n + 1] = 1.f - w0;
    }
}

// ---------------------------------------------------------------------------
// Dispatch: exact token-major (i = n*2+k) capacity ranking, single block.
// routerEx staged once into LDS (u8, padded +1B per 128) via coalesced
// global reads; both passes then hit LDS instead of stride-128 HBM.
// ---------------------------------------------------------------------------
__global__ __launch_bounds__(256) void dispatch_kernel(
    const int* __restrict__ routerEx, int* __restrict__ tokenSlot,
    int* __restrict__ slotToken, int* __restrict__ cnt)
{
    __shared__ u8  exs[NK + NK / 128];   // 33 KB
    __shared__ int hist[256 * E_];       // 8 KB
    int t = threadIdx.x;
    for (int i = t; i < NK; i += 256)
        exs[i + (i >> 7)] = (u8)routerEx[i];
    __syncthreads();
    int loc[E_];
#pragma unroll
    for (int e = 0; e < E_; ++e) loc[e] = 0;
    int abase = t * 129;                 // t*128 + pad(t)
    for (int j = 0; j < NK / 256; ++j) {
        int ev = exs[abase + j];
#pragma unroll
        for (int e = 0; e < E_; ++e) loc[e] += (ev == e) ? 1 : 0;
    }
#pragma unroll
    for (int e = 0; e < E_; ++e) hist[t * E_ + e] = loc[e];
    __syncthreads();
    if (t < E_) {
        int run = 0;
        for (int tt = 0; tt < 256; ++tt) { int v = hist[tt * E_ + t]; hist[tt * E_ + t] = run; run += v; }
        cnt[t] = run;
    }
    __syncthreads();
    int off[E_];
#pragma unroll
    for (int e = 0; e < E_; ++e) off[e] = hist[t * E_ + e];
    int base = t * (NK / 256);
    for (int j = 0; j < NK / 256; ++j) {
        int i = base + j;
        int ev = exs[abase + j];
        int pos = 0;
#pragma unroll
        for (int e = 0; e < E_; ++e) { if (ev == e) { pos = off[e]; off[e] = pos + 1; } }
        if (pos < CAP) {
            int s = ev * CAP + pos;
            tokenSlot[i] = s;
            slotToken[s] = i;
        } else {
            tokenSlot[i] = -1;
        }
    }
}

// ---------------------------------------------------------------------------
// init_out: out[n] = (sum kept w) * x[n]   (per-expert path only)
// ---------------------------------------------------------------------------
__global__ __launch_bounds__(256) void init_out_kernel(
    const float* __restrict__ x, const int* __restrict__ tokenSlot,
    const float* __restrict__ routerW, float* __restrict__ out)
{
    int g = blockIdx.x * 256 + threadIdx.x;
    int n = g / 96;
    int d0 = (g - n * 96) * 8;
    float w0 = (tokenSlot[2 * n] >= 0) ? routerW[2 * n] : 0.f;
    float w1 = (tokenSlot[2 * n + 1] >= 0) ? routerW[2 * n + 1] : 0.f;
    float ws = w0 + w1;
    const float* xr = x + (size_t)n * D_ + d0;
    float* orow = out + (size_t)n * D_ + d0;
    float4 a = *(const float4*)&xr[0];
    float4 b = *(const float4*)&xr[4];
    float4 oa, ob;
    oa.x = ws * a.x; oa.y = ws * a.y; oa.z = ws * a.z; oa.w = ws * a.w;
    ob.x = ws * b.x; ob.y = ws * b.y; ob.z = ws * b.z; ob.w = ws * b.w;
    *(float4*)&orow[0] = oa;
    *(float4*)&orow[4] = ob;
}

// ---------------------------------------------------------------------------
// Gather + RMSNorm: zE[pos] = bf16(2x*rsqrt(mean((2x)^2)+eps)*nw[e]).
// e = eFixed + blockIdx.z; z rows beyond count written as zeros.
// z stays LINEAR row-major (the gemm1 stager applies the swizzle at read).
// ---------------------------------------------------------------------------
__global__ __launch_bounds__(256) void gather_norm_kernel(
    const float* __restrict__ x, const float* __restrict__ norm_w,
    const int* __restrict__ slotToken, const int* __restrict__ cnt,
    u16* __restrict__ zAll, size_t zStride, int eFixed)
{
    int e = eFixed + blockIdx.z;
    u16* zE = zAll + (size_t)blockIdx.z * zStride;
    int t = threadIdx.x, wv = t >> 6, l = t & 63;
    int pos = blockIdx.x * 4 + wv;
    int ce = min(cnt[e], CAP);
    u16* zr = zE + (size_t)pos * D_;
    if (pos >= ce) {
        ushort4 zz = { 0, 0, 0, 0 };
#pragma unroll
        for (int j = 0; j < 3; ++j) *(ushort4*)&zr[l * 4 + 256 * j] = zz;
        return;
    }
    int tok = slotToken[e * CAP + pos] >> 1;
    const float* xr = x + (size_t)tok * D_;
    float xv[12]; float ss = 0.f;
#pragma unroll
    for (int j = 0; j < 3; ++j) {
        float4 v4 = *(const float4*)&xr[l * 4 + 256 * j];
        xv[4 * j] = v4.x; xv[4 * j + 1] = v4.y; xv[4 * j + 2] = v4.z; xv[4 * j + 3] = v4.w;
        ss += v4.x * v4.x + v4.y * v4.y + v4.z * v4.z + v4.w * v4.w;
    }
#pragma unroll
    for (int off = 32; off > 0; off >>= 1) ss += __shfl_xor(ss, off, 64);
    float rs = rsqrtf(4.f * ss * (1.f / (float)D_) + EPS_);
    const float* nw = norm_w + e * D_;
#pragma unroll
    for (int j = 0; j < 3; ++j) {
        int d0 = l * 4 + 256 * j;
        float4 nv = *(const float4*)&nw[d0];
        ushort4 o;
        o.x = f2bf(2.f * xv[4 * j]     * rs * nv.x);
        o.y = f2bf(2.f * xv[4 * j + 1] * rs * nv.y);
        o.z = f2bf(2.f * xv[4 * j + 2] * rs * nv.z);
        o.w = f2bf(2.f * xv[4 * j + 3] * rs * nv.w);
        *(ushort4*)&zr[d0] = o;
    }
}

// ---------------------------------------------------------------------------
// GEMM1: gu = zE @ w13e^T, tile 128 x (64g+64u), BK=64, K=768, fused SwiGLU.
// m97 structure: global_load_lds(16B) into linear swizzled LDS, 2 barriers
// per K-step, MFMA 16x16x32.  XCD chunk swizzle 8jn x 20rb.
// ---------------------------------------------------------------------------
__global__ __launch_bounds__(256, 2) void gemm1_kernel(
    const u16* __restrict__ zAll, size_t zStride,
    const u16* __restrict__ w13All, size_t wStride,
    u16* __restrict__ actAll, size_t actStride,
    const int* __restrict__ cnt, int eFixed)
{
    // bijective XCD swizzle over the 32x40 plane: chunk = 8 jn x 20 rb
    int hw  = blockIdx.y * 32 + blockIdx.x;
    int xcd = hw & 7, cid = hw >> 3;            // cid in [0,160)
    int jn  = (xcd & 3) * 8 + (cid & 7);        // 0..31
    int rb  = (xcd >> 2) * 20 + (cid >> 3);     // 0..39
    int e   = eFixed + blockIdx.z;
    int ce  = min(cnt[e], CAP);
    if (rb * 128 >= ce) return;
    const u16* zE   = zAll   + (size_t)blockIdx.z * zStride;
    const u16* w13e = w13All + (size_t)blockIdx.z * wStride;
    u16*       actE = actAll + (size_t)blockIdx.z * actStride;

    __shared__ __align__(16) u16 smem[2 * 128 * 64];   // 32 KB, linear
    u16* As = smem;             // [128][64] u16, XOR-swizzled content
    u16* Bs = smem + 128 * 64;

    int t = threadIdx.x, w = t >> 6, l = t & 63;
    int lr  = l >> 3;                        // row within 8-row group
    int lsw = ((l & 7) ^ lr) << 4;           // inverse-swizzled src col byte

    // per-lane global sources (linear z/w13, swizzle folded into col offset)
    const char* aSrc = (const char*)zE
        + (size_t)(rb * 128 + w * 32 + lr) * (D_ * 2) + lsw;
    int rr0   = w * 32 + lr;                              // waves 0,1: g; 2,3: u
    int grow0 = (w < 2) ? (jn * 64 + rr0) : (H_ + jn * 64 + (rr0 - 64));
    const char* bSrc = (const char*)w13e + (size_t)grow0 * (D_ * 2) + lsw;

    const v4f vzero = { 0.f, 0.f, 0.f, 0.f };
    v4f acc[2][8];
#pragma unroll
    for (int i = 0; i < 2; ++i)
#pragma unroll
        for (int j = 0; j < 8; ++j) acc[i][j] = vzero;

    int fr = l & 15;              // fragment row select
    int sw = (l & 7) << 4;        // read-side XOR (row&7)<<4, row&7 == l&7
    int fq = (l >> 4) << 4;       // k-quarter byte offset

    for (int kb = 0; kb < D_ / 64; ++kb) {
        __syncthreads();          // prior MFMA reads done before overwrite
#pragma unroll
        for (int i = 0; i < 4; ++i) {
            gload16(aSrc + i * (8 * D_ * 2), &As[(w * 32 + i * 8) * 64]);
            gload16(bSrc + i * (8 * D_ * 2), &Bs[(w * 32 + i * 8) * 64]);
        }
        aSrc += 128; bSrc += 128;
        __syncthreads();          // compiler drains vmcnt(0) -> LDS valid
#pragma unroll
        for (int ks = 0; ks < 2; ++ks) {
            int kby = (ks * 64 + fq) ^ sw;
            v8bf a0 = *(const v8bf*)((const char*)As + (w * 32      + fr) * 128 + kby);
            v8bf a1 = *(const v8bf*)((const char*)As + (w * 32 + 16 + fr) * 128 + kby);
            v8bf bv[8];
#pragma unroll
            for (int ct = 0; ct < 8; ++ct)
                bv[ct] = *(const v8bf*)((const char*)Bs + (ct * 16 + fr) * 128 + kby);
#pragma unroll
            for (int ct = 0; ct < 8; ++ct) {
                acc[0][ct] = __builtin_amdgcn_mfma_f32_16x16x32_bf16(a0, bv[ct], acc[0][ct], 0, 0, 0);
                acc[1][ct] = __builtin_amdgcn_mfma_f32_16x16x32_bf16(a1, bv[ct], acc[1][ct], 0, 0, 0);
            }
        }
    }
    // epilogue: act = silu(g)*u, staged in padded LDS then coalesced stores.
    __syncthreads();
    u16* ep = smem;               // [128][LDE] view, 9216 u16 <= 16384
    int colb = l & 15, rowq = (l >> 4) * 4;
#pragma unroll
    for (int rt = 0; rt < 2; ++rt) {
#pragma unroll
        for (int cg = 0; cg < 4; ++cg) {
            v4f g = acc[rt][cg], u = acc[rt][cg + 4];
#pragma unroll
            for (int r = 0; r < 4; ++r) {
                int rl = w * 32 + rt * 16 + rowq + r;
                float gv = g[r], uv = u[r];
                ep[rl * LDE + cg * 16 + colb] = f2bf(gv / (1.f + __expf(-gv)) * uv);
            }
        }
    }
    __syncthreads();
#pragma unroll
    for (int i = 0; i < 4; ++i) {
        int rl = (t >> 3) + 32 * i;
        int c0 = (t & 7) * 8;
        uint4 v = *(const uint4*)&ep[rl * LDE + c0];
        *(uint4*)&actE[(size_t)(rb * 128 + rl) * H_ + jn * 64 + c0] = v;
    }
}

// ---------------------------------------------------------------------------
// GEMM2: delta = actE @ w2e^T, tile 128 x 128, BK=64, K=2048.  Same m97
// structure/inner loop as gemm1.  XCD chunk swizzle 6jn x 5rb.  Epilogue
// in two 64-col halves through LDS.  WRITE_DELTA ? coalesced bf16 delta
// stores : coalesced fp32 RMW into out rows (serialized path).
// ---------------------------------------------------------------------------
template <bool WRITE_DELTA>
__global__ __launch_bounds__(256, 2) void gemm2_kernel(
    const u16* __restrict__ actAll, size_t actStride,
    const u16* __restrict__ w2All, size_t wStride,
    const int* __restrict__ slotToken, const float* __restrict__ routerW,
    float* __restrict__ out, u16* __restrict__ deltaAll, size_t deltaStride,
    const int* __restrict__ cnt, int eFixed)
{
    // bijective XCD swizzle over the 6x40 plane: chunk = 6 jn x 5 rb
    int hw  = blockIdx.y * 6 + blockIdx.x;      // 0..239
    int xcd = hw & 7, cid = hw >> 3;            // cid in [0,30)
    int jn  = cid % 6;                          // 0..5  (cols [jn*128, +128))
    int rb  = xcd * 5 + cid / 6;                // 0..39
    int e   = eFixed + blockIdx.z;
    int ce  = min(cnt[e], CAP);
    if (rb * 128 >= ce) return;
    const u16* actE = actAll + (size_t)blockIdx.z * actStride;
    const u16* w2e  = w2All  + (size_t)blockIdx.z * wStride;

    __shared__ __align__(16) u16 smem[2 * 128 * 64];   // 32 KB
    u16* As = smem;             // [128][64]
    u16* Bs = smem + 128 * 64;  // [128][64]

    int t = threadIdx.x, w = t >> 6, l = t & 63;
    int lr  = l >> 3;
    int lsw = ((l & 7) ^ lr) << 4;

    const char* aSrc = (const char*)actE
        + (size_t)(rb * 128 + w * 32 + lr) * (H_ * 2) + lsw;
    const char* bSrc = (const char*)w2e
        + (size_t)(jn * 128 + w * 32 + lr) * (H_ * 2) + lsw;

    const v4f vzero = { 0.f, 0.f, 0.f, 0.f };
    v4f acc[2][8];
#pragma unroll
    for (int i = 0; i < 2; ++i)
#pragma unroll
        for (int j = 0; j < 8; ++j) acc[i][j] = vzero;

    int fr = l & 15;
    int sw = (l & 7) << 4;
    int fq = (l >> 4) << 4;

    for (int kb = 0; kb < H_ / 64; ++kb) {
        __syncthreads();
#pragma unroll
        for (int i = 0; i < 4; ++i) {
            gload16(aSrc + i * (8 * H_ * 2), &As[(w * 32 + i * 8) * 64]);
            gload16(bSrc + i * (8 * H_ * 2), &Bs[(w * 32 + i * 8) * 64]);
        }
        aSrc += 128; bSrc += 128;
        __syncthreads();
#pragma unroll
        for (int ks = 0; ks < 2; ++ks) {
            int kby = (ks * 64 + fq) ^ sw;
            v8bf a0 = *(const v8bf*)((const char*)As + (w * 32      + fr) * 128 + kby);
            v8bf a1 = *(const v8bf*)((const char*)As + (w * 32 + 16 + fr) * 128 + kby);
            v8bf bv[8];
#pragma unroll
            for (int ct = 0; ct < 8; ++ct)
                bv[ct] = *(const v8bf*)((const char*)Bs + (ct * 16 + fr) * 128 + kby);
#pragma unroll
            for (int ct = 0; ct < 8; ++ct) {
                acc[0][ct] = __builtin_amdgcn_mfma_f32_16x16x32_bf16(a0, bv[ct], acc[0][ct], 0, 0, 0);
                acc[1][ct] = __builtin_amdgcn_mfma_f32_16x16x32_bf16(a1, bv[ct], acc[1][ct], 0, 0, 0);
            }
        }
    }
    // epilogue: two 64-col halves through the LDS buffer.
    u16* ep = smem;               // [128][LDE] view
    int colb = l & 15, rowq = (l >> 4) * 4;
#pragma unroll
    for (int h = 0; h < 2; ++h) {
        __syncthreads();          // prior reads (MFMA or previous half) done
#pragma unroll
        for (int rt = 0; rt < 2; ++rt) {
#pragma unroll
            for (int cc = 0; cc < 4; ++cc) {
                v4f a = acc[rt][h * 4 + cc];
#pragma unroll
                for (int r = 0; r < 4; ++r) {
                    int rl = w * 32 + rt * 16 + rowq + r;
                    ep[rl * LDE + cc * 16 + colb] = f2bf(a[r]);
                }
            }
        }
        __syncthreads();
        if (WRITE_DELTA) {
            u16* deltaE = deltaAll + (size_t)blockIdx.z * deltaStride;
#pragma unroll
            for (int i = 0; i < 4; ++i) {
                int rl = (t >> 3) + 32 * i;
                int c0 = (t & 7) * 8;
                uint4 v = *(const uint4*)&ep[rl * LDE + c0];
                *(uint4*)&deltaE[(size_t)(rb * 128 + rl) * D_ + jn * 128 + h * 64 + c0] = v;
            }
        } else {
            // fp32 RMW into out rows (experts serialized -> race-free)
#pragma unroll
            for (int i = 0; i < 8; ++i) {
                int rl = (t >> 4) + 16 * i;
                int grow = rb * 128 + rl;
                if (grow >= ce) continue;
                int idx = slotToken[e * CAP + grow];
                int tok = idx >> 1;
                float wg = routerW[idx];
                int c = (t & 15) * 4;
                const u16* dr = &ep[rl * LDE + c];
                float* orow = out + (size_t)tok * D_ + jn * 128 + h * 64 + c;
                float4 cur = *(const float4*)orow;
                cur.x += wg * bf2f(dr[0]);
                cur.y += wg * bf2f(dr[1]);
                cur.z += wg * bf2f(dr[2]);
                cur.w += wg * bf2f(dr[3]);
                *(float4*)orow = cur;
            }
        }
    }
}

// ---------------------------------------------------------------------------
// Combine (batched path): out[n] = ws*x[n] + w0*delta[s0] + w1*delta[s1]
// ---------------------------------------------------------------------------
__global__ __launch_bounds__(256) void combine_kernel(
    const float* __restrict__ x, const u16* __restrict__ deltaBuf,
    const int* __restrict__ tokenSlot, const float* __restrict__ routerW,
    float* __restrict__ out)
{
    int g = blockIdx.x * 256 + threadIdx.x;  // one float4 per thread
    int n = g / 192;
    int d0 = (g - n * 192) * 4;
    int s0 = tokenSlot[2 * n], s1 = tokenSlot[2 * n + 1];
    float w0 = (s0 >= 0) ? routerW[2 * n] : 0.f;
    float w1 = (s1 >= 0) ? routerW[2 * n + 1] : 0.f;
    float ws = w0 + w1;
    float4 xv = *(const float4*)&x[(size_t)n * D_ + d0];
    float4 o;
    o.x = ws * xv.x; o.y = ws * xv.y; o.z = ws * xv.z; o.w = ws * xv.w;
    if (s0 >= 0) {
        ushort4 dv = *(const ushort4*)&deltaBuf[(size_t)s0 * D_ + d0];
        o.x += w0 * bf2f(dv.x); o.y += w0 * bf2f(dv.y);
        o.z += w0 * bf2f(dv.z); o.w += w0 * bf2f(dv.w);
    }
    if (s1 >= 0) {
        ushort4 dv = *(const ushort4*)&deltaBuf[(size_t)s1 * D_ + d0];
        o.x += w1 * bf2f(dv.x); o.y += w1 * bf2f(dv.y);
        o.z += w1 * bf2f(dv.z); o.w += w1 * bf2f(dv.w);
    }
    *(float4*)&out[(size_t)n * D_ + d0] = o;
}

// ---------------------------------------------------------------------------
extern "C" void kernel_launch(void* const* d_in, const int* in_sizes, int n_in,
                              void* d_out, int out_size, void* d_ws, size_t ws_size,
                              hipStream_t stream)
{
    (void)in_sizes; (void)n_in; (void)out_size;
    const float* x      = (const float*)d_in[0];
    const float* gate_w = (const float*)d_in[1];
    const float* w13    = (const float*)d_in[2];
    const float* w2     = (const float*)d_in[3];
    const float* norm_w = (const float*)d_in[4];
    float* out = (float*)d_out;

    const size_t zSlice   = (size_t)CAP * D_ * 2;       // 7.9 MB
    const size_t actSlice = (size_t)CAP * H_ * 2;       // 21 MB
    const size_t w13Slice = (size_t)2 * H_ * D_ * 2;    // 6.3 MB
    const size_t w2Slice  = (size_t)D_ * H_ * 2;        // 3.1 MB
    const size_t ctrl     = (size_t)NK * 4 * 3 + (size_t)E_ * CAP * 4 + 256;

    char* ws = (char*)d_ws;
    size_t off = 0;
    int*   routerEx  = (int*)(ws + off);   off += (size_t)NK * 4;
    float* routerW   = (float*)(ws + off); off += (size_t)NK * 4;
    int*   tokenSlot = (int*)(ws + off);   off += (size_t)NK * 4;
    int*   slotToken = (int*)(ws + off);   off += (size_t)E_ * CAP * 4;
    int*   cnt       = (int*)(ws + off);   off += 256;

    const size_t bigNeed = ctrl + E_ * (zSlice + actSlice + w13Slice + w2Slice) + E_ * zSlice /*delta*/;
    bool batched = ws_size >= bigNeed;

    router_kernel<<<N_TOK / 4, 256, 0, stream>>>(x, gate_w, routerEx, routerW);
    dispatch_kernel<<<1, 256, 0, stream>>>(routerEx, tokenSlot, slotToken, cnt);

    if (batched) {
        u16* zBuf     = (u16*)(ws + off); off += E_ * zSlice;
        u16* actBuf   = (u16*)(ws + off); off += E_ * actSlice;
        u16* deltaBuf = (u16*)(ws + off); off += E_ * zSlice;
        u16* w13bf    = (u16*)(ws + off); off += E_ * w13Slice;
        u16* w2bf     = (u16*)(ws + off); off += E_ * w2Slice;

        int n13 = E_ * 2 * H_ * D_ / 4, n2 = E_ * D_ * H_ / 4;
        conv_bf16_kernel<<<(n13 + 255) / 256, 256, 0, stream>>>(w13, w13bf, n13);
        conv_bf16_kernel<<<(n2 + 255) / 256, 256, 0, stream>>>(w2, w2bf, n2);
        gather_norm_kernel<<<dim3(CAP / 4, 1, E_), 256, 0, stream>>>(
            x, norm_w, slotToken, cnt, zBuf, zSlice / 2, 0);
        gemm1_kernel<<<dim3(H_ / 64, CAP / 128, E_), 256, 0, stream>>>(
            zBuf, zSlice / 2, w13bf, w13Slice / 2, actBuf, actSlice / 2, cnt, 0);
        gemm2_kernel<true><<<dim3(D_ / 128, CAP / 128, E_), 256, 0, stream>>>(
            actBuf, actSlice / 2, w2bf, w2Slice / 2, slotToken, routerW,
            out, deltaBuf, zSlice / 2, cnt, 0);
        combine_kernel<<<(N_TOK * (D_ / 4)) / 256, 256, 0, stream>>>(
            x, deltaBuf, tokenSlot, routerW, out);
    } else {
        u16* zE   = (u16*)(ws + off); off += zSlice;
        u16* actE = (u16*)(ws + off); off += actSlice;
        u16* w13e = (u16*)(ws + off); off += w13Slice;
        u16* w2e  = (u16*)(ws + off); off += w2Slice;

        init_out_kernel<<<(N_TOK * (D_ / 8)) / 256, 256, 0, stream>>>(x, tokenSlot, routerW, out);
        int n13 = 2 * H_ * D_ / 4, n2 = D_ * H_ / 4;
        for (int e = 0; e < E_; ++e) {
            conv_bf16_kernel<<<(n13 + 255) / 256, 256, 0, stream>>>(
                w13 + (size_t)e * 2 * H_ * D_, w13e, n13);
            conv_bf16_kernel<<<(n2 + 255) / 256, 256, 0, stream>>>(
                w2 + (size_t)e * D_ * H_, w2e, n2);
            gather_norm_kernel<<<dim3(CAP / 4, 1, 1), 256, 0, stream>>>(
                x, norm_w, slotToken, cnt, zE, 0, e);
            gemm1_kernel<<<dim3(H_ / 64, CAP / 128, 1), 256, 0, stream>>>(
                zE, 0, w13e, 0, actE, 0, cnt, e);
            gemm2_kernel<false><<<dim3(D_ / 128, CAP / 128, 1), 256, 0, stream>>>(
                actE, 0, w2e, 0, slotToken, routerW, out, (u16*)nullptr, 0, cnt, e);
        }
    }
}